// Round 18
// baseline (151.387 us; speedup 1.0000x reference)
//
#include <hip/hip_runtime.h>
#include <hip/hip_bf16.h>
#include <math.h>

// Problem constants (img 2048x2048, strides 4..64, 3 anchors/loc)
#define K_TOP 1000
#define NLEV  5
#define NSEL  5000          // 5 * 1000 candidates
#define NCH   79            // ceil(5000/64) chunks of 64 candidates
#define NP    5000          // u64 row stride of transposed mask: maskT[w*NP + i]
#define NW    80            // allocated word-rows (0..78 used)
#define NSTG  20            // chunks whose lower triangle is LDS-staged in k_nms
#define NPAIR 210           // T(NSTG) = 20*21/2 pair-words
#define ATOT  1047552
#define BBOX_CLIP_F 4.135166556742356f

// ws layout in u32 units
#define INFO1   0          // 5*4: [binstar, above, need, pad]
#define CANDCNT 32         // 5 (own 128B line)
#define EQCNT   64         // 5
#define MAXC    96         // 1 (float bits)
#define DONEC   128        // 5 (k_red election counters)
#define HIST1   256        // 5*2048 reduced hist -> ends 10496
#define CANDO   10496      // 5*1024 per-level local indices -> 15616
#define EQO     15616      // u64[5*4096] = 40960 u32 -> 56576 (byte 62464 %8==0)
#define KEYS2   56576      // u64[5000] = 10000 u32 -> 66576 (byte 226304 %8==0)
#define SORTCP  66576      // u32[5120] -> 71696
#define BOXA    71696      // f32[5120][4] -> 92176
#define VALIDA  92176      // u32[5120] -> 97296
#define NBSO    97296      // f32[5120][4] -> 117776
#define AREAS   117776     // f32[5120] -> 122896
#define VALSB   122896     // u32[160] 5000-bit valid mask (byte 491584 %8==0)
#define MASKO   124080     // u64[NW*NP] (byte 496320 %16==0) -> ends 924080 u32
#define PARTH   1048576    // u32[512*2048] per-block partial hists (byte 4MB, 4MB long)

__device__ __forceinline__ int loff(int l){
  return (l==0)?0:(l==1)?786432:(l==2)?983040:(l==3)?1032192:1044480;
}
// monotonic uint32 key: larger float <-> larger key
__device__ __forceinline__ unsigned fmono(float x){
  unsigned b=__float_as_uint(x);
  return (b&0x80000000u)? ~b : (b|0x80000000u);
}

// inclusive block scan over 1024 threads (shuffle waves + 16-wave combine); 2 barriers.
__device__ __forceinline__ unsigned blockscan1024(unsigned v, unsigned* wbuf, int t){
  int lane = t&63, wid = t>>6;
  #pragma unroll
  for (int d=1; d<64; d<<=1){
    unsigned u = __shfl_up(v, d, 64);
    if (lane>=d) v += u;
  }
  if (lane==63) wbuf[wid]=v;
  __syncthreads();
  if (wid==0){
    unsigned w = (lane<16)? wbuf[lane] : 0u;
    #pragma unroll
    for (int d=1; d<16; d<<=1){
      unsigned u=__shfl_up(w,d,64);
      if (lane>=d) w+=u;
    }
    if (lane<16) wbuf[lane]=w;
  }
  __syncthreads();
  unsigned off = (wid>0)? wbuf[wid-1] : 0u;
  return v+off;
}

// pass-1 histogram (bits 31..21): flat 512-block grid (2048 contiguous elems/block,
// each block inside ONE level since level bounds are multiples of 2048), float4 loads,
// 8x replicated LDS hist. Writes per-block PARTIAL hist (plain coalesced stores).
// FOLDS init: each block zeroes a disjoint 21-word control-region slice.
__global__ void k_hist1(const float* __restrict__ obj, unsigned* ws32){
  int b = blockIdx.x;                 // 512 blocks
  int t = threadIdx.x;                // 256
  if (t<21){
    int idx = b*21 + t;
    if (idx < 10496) ws32[idx]=0u;
    else if (idx < 10656) ws32[VALSB + (idx-10496)]=0u;
  }
  int rep = t & 7;
  __shared__ unsigned h[2048*8];      // 64 KiB replicated hist
  for (int i=t; i<2048*8; i+=256) h[i]=0u;
  __syncthreads();
  const float4* src = (const float4*)(obj + (size_t)b*2048);
  int nVec = (b==511)? 256 : 512;     // tail block has 1024 elems
  for (int i=t; i<nVec; i+=256){
    float4 v = src[i];
    atomicAdd(&h[(fmono(v.x)>>21)*8 + rep], 1u);
    atomicAdd(&h[(fmono(v.y)>>21)*8 + rep], 1u);
    atomicAdd(&h[(fmono(v.z)>>21)*8 + rep], 1u);
    atomicAdd(&h[(fmono(v.w)>>21)*8 + rep], 1u);
  }
  __syncthreads();
  unsigned* dst = ws32 + PARTH + (size_t)b*2048;
  for (int bin=t; bin<2048; bin+=256){
    unsigned v=0;
    #pragma unroll
    for (int r=0;r<8;r++) v += h[bin*8+r];
    dst[bin]=v;                       // plain store; cross-kernel visibility via dispatch order
  }
}

// tiled reduction of partial hists: grid (8 bin-chunks, 18 tiles). Each tile sums <=32
// partials of one level with 4-way unrolled independent accumulators (latency-parallel),
// atomicAdd per NON-ZERO bin. Last tile-block per level runs the descending scan -> INFO1.
__global__ void k_red(unsigned* ws32){
  int c = blockIdx.x;        // 8 bin chunks x 256 bins
  int ty = blockIdx.y;       // 18 tiles
  int t = threadIdx.x;       // 256
  int l, p0, np;
  if (ty<12){ l=0; p0=ty*32; np=32; }
  else if (ty<15){ l=1; p0=384+(ty-12)*32; np=32; }
  else if (ty==15){ l=2; p0=480; np=24; }
  else if (ty==16){ l=3; p0=504; np=6; }
  else { l=4; p0=510; np=2; }
  int bin = (c<<8) + t;
  const unsigned* part = ws32 + PARTH;
  unsigned s0=0,s1=0,s2=0,s3=0;
  int k=0;
  for (; k+4<=np; k+=4){
    s0 += part[(size_t)(p0+k  )*2048 + bin];
    s1 += part[(size_t)(p0+k+1)*2048 + bin];
    s2 += part[(size_t)(p0+k+2)*2048 + bin];
    s3 += part[(size_t)(p0+k+3)*2048 + bin];
  }
  for (; k<np; ++k) s0 += part[(size_t)(p0+k)*2048 + bin];
  unsigned sum = s0+s1+s2+s3;
  if (sum) atomicAdd(&ws32[HIST1 + l*2048 + bin], sum);
  // per-level election (blocks per level: 96,24,8,8,8)
  __shared__ unsigned isLast;
  __shared__ unsigned h2[2048];
  __shared__ unsigned psum[256];
  __threadfence();
  if (t==0){
    unsigned nb = (l==0)?96u:(l==1)?24u:8u;
    unsigned old = atomicAdd(&ws32[DONEC+l],1u);
    isLast = (old==nb-1u)?1u:0u;
  }
  __syncthreads();
  if (!isLast) return;
  __threadfence();
  for (int i=t;i<2048;i+=256) h2[i]=atomicAdd(&ws32[HIST1+l*2048+i],0u);  // coherent re-read
  __syncthreads();
  unsigned local=0;
  for (int r=t*8; r<t*8+8; r++) local += h2[2047-r];
  psum[t]=local; __syncthreads();
  for (int s=1;s<256;s<<=1){
    unsigned v=(t>=s)?psum[t-s]:0u;
    __syncthreads();
    psum[t]+=v;
    __syncthreads();
  }
  unsigned excl=(t==0)?0u:psum[t-1];
  if (excl < K_TOP && psum[t] >= K_TOP){
    unsigned cum=excl;
    for (int r=t*8; r<t*8+8; r++){
      unsigned hv=h2[2047-r];
      if (cum+hv >= K_TOP){
        ws32[INFO1+l*4+0]=(unsigned)(2047-r); // boundary bin b*
        ws32[INFO1+l*4+1]=cum;                // count in strictly greater bins
        ws32[INFO1+l*4+2]=K_TOP-cum;          // needed from bin b*
        break;
      }
      cum+=hv;
    }
  }
}

// single full scan, block-local LDS aggregation: flat 512x2048 grid (one level per
// block). Hits appended to LDS lists; ONE global atomicAdd per list per block at the
// end + bulk copy-out. Order within a level is irrelevant (re-sorted downstream).
__global__ void k_collect(const float* __restrict__ obj, unsigned* ws32){
  int b = blockIdx.x;                 // 512 blocks x 256 threads
  int t = threadIdx.x;
  int l = (b<384)?0:(b<480)?1:(b<504)?2:(b<510)?3:4;
  unsigned bstar = ws32[INFO1 + l*4];
  int lof = loff(l);
  __shared__ unsigned candL[1024];          // per-level greater-bin total < 1000
  __shared__ unsigned long long eqL[2048];
  __shared__ unsigned ncS, neS, b1S, b2S;
  if (t==0){ ncS=0u; neS=0u; }
  __syncthreads();
  const float4* src = (const float4*)(obj + (size_t)b*2048);
  int nVec = (b==511)? 256 : 512;
  for (int i=t; i<nVec; i+=256){
    float4 f = src[i];
    #pragma unroll
    for (int q=0;q<4;q++){
      float x = (q==0)?f.x:(q==1)?f.y:(q==2)?f.z:f.w;
      unsigned key = fmono(x);
      unsigned bin = key>>21;
      unsigned idx = (unsigned)(b*2048 + 4*i + q - lof);
      if (bin > bstar){
        unsigned p = atomicAdd(&ncS,1u);
        if (p<1024u) candL[p]=idx;
      } else if (bin == bstar){
        unsigned p = atomicAdd(&neS,1u);
        if (p<2048u) eqL[p] = (((unsigned long long)(~key))<<20) | idx;
      }
    }
  }
  __syncthreads();
  unsigned nc = ncS>1024u?1024u:ncS, ne = neS>2048u?2048u:neS;
  if (t==0){
    b1S = nc? atomicAdd(&ws32[CANDCNT+l], nc) : 0u;
    b2S = ne? atomicAdd(&ws32[EQCNT+l],  ne) : 0u;
  }
  __syncthreads();
  unsigned base1=b1S, base2=b2S;
  unsigned long long* eq64 = (unsigned long long*)(ws32+EQO) + (size_t)l*4096;
  for (unsigned i=t; i<nc; i+=256){
    unsigned p = base1+i;
    if (p<1024u) ws32[CANDO + l*1024 + p] = candL[i];
  }
  for (unsigned i=t; i<ne; i+=256){
    unsigned p = base2+i;
    if (p<4096u) eq64[p] = eqL[i];
  }
}

// fused per-level (1024 threads, 1 block/level):
//  phase A: exact 4-level radix SELECT of the `need` smallest (m,idx) boundary-bin keys.
//  phase B: rank-sort the 1000 selected, decode+clip+valid+sigmoid, stable valid-partition
//           -> KEYS2 (plain stores; kernel boundary gives visibility to k_mergeprep).
__global__ void k_tailfuse(const float* __restrict__ obj, const float* __restrict__ deltas,
                           const float* __restrict__ anchors, unsigned* ws32){
  int l = blockIdx.x, t = threadIdx.x;   // 5 x 1024
  __shared__ unsigned long long big[4096];    // 32KB: phase A key buf
  __shared__ unsigned long long karr[1024];   // phase-B keys
  __shared__ unsigned hist[2048];             // phase A hist; phase B pfx aliases [0..1023]
  __shared__ unsigned selidx[1024];
  __shared__ unsigned char st[4096];          // 0=TIE 1=SEL 2=REJ
  __shared__ unsigned wbuf[16];
  __shared__ unsigned sdS, scltS, sneeS, scntS, nvS;
  int off = loff(l);
  unsigned cnt = ws32[EQCNT+l]; if (cnt>4096u) cnt=4096u;
  unsigned base = ws32[CANDCNT+l];
  unsigned need = ws32[INFO1+l*4+2];
  const unsigned long long* eq = (const unsigned long long*)(ws32+EQO) + (size_t)l*4096;
  for (int i=t;i<(int)cnt;i+=1024){ big[i]=eq[i]; st[i]=0; }
  if (t==0) sneeS = need;
  __syncthreads();
  // ---- phase A: 4-level radix select ----
  #pragma unroll
  for (int lev=0; lev<4; ++lev){
    int sh = (lev==0)?30:(lev==1)?20:(lev==2)?10:0;
    unsigned msk = (lev==0)?0x7FFu:0x3FFu;
    hist[2*t]=0u; hist[2*t+1]=0u;
    __syncthreads();
    for (int i=t;i<(int)cnt;i+=1024)
      if (st[i]==0) atomicAdd(&hist[(unsigned)((big[i]>>sh)&msk)],1u);
    __syncthreads();
    unsigned h0=hist[2*t], h1=hist[2*t+1];
    unsigned incl = blockscan1024(h0+h1, wbuf, t);
    unsigned cumprev = incl - h0 - h1;
    unsigned needc = sneeS;
    if (cumprev < needc && needc <= cumprev+h0){ sdS=(unsigned)(2*t); scltS=cumprev; }
    else if (cumprev+h0 < needc && needc <= incl){ sdS=(unsigned)(2*t+1); scltS=cumprev+h0; }
    __syncthreads();
    unsigned dstar=sdS, clt=scltS;
    if (t==0) sneeS -= clt;
    for (int i=t;i<(int)cnt;i+=1024){
      if (st[i]==0){
        unsigned d=(unsigned)((big[i]>>sh)&msk);
        st[i] = (d<dstar)?1u: (d>dstar)?2u:0u;
      }
    }
    __syncthreads();
  }
  if (t==0) scntS = base;
  __syncthreads();
  for (int i=t;i<(int)cnt;i+=1024)
    if (st[i]!=2u){ unsigned p=atomicAdd(&scntS,1u); if (p<1024u) selidx[p]=(unsigned)(big[i]&0xFFFFFULL); }
  if (t<(int)base) selidx[t]=ws32[CANDO+l*1024+t];
  __syncthreads();
  // ---- phase B: rank-sort + decode ----
  unsigned idx_t = (t<K_TOP)? selidx[t] : 0u;
  unsigned long long mykey;
  if (t<K_TOP){
    unsigned m = ~fmono(obj[off+idx_t]);
    mykey = (((unsigned long long)m)<<20) | idx_t;
  } else mykey = ~0ULL;
  karr[t]=mykey;
  __syncthreads();
  int j = 0;
  if (t<K_TOP){
    #pragma unroll 4
    for (int u=0; u<K_TOP; ++u) j += (karr[u] < mykey) ? 1 : 0;
  }
  unsigned valid=0u;
  unsigned long long key64=~0ULL;
  int s = (l<<10)|j;
  if (t<K_TOP){
    int g = off + (int)idx_t;
    float o = obj[g];
    const float* dd = deltas + 4*(size_t)g;
    const float* aa = anchors + 4*(size_t)g;
    float dx=dd[0], dy=dd[1], dw=dd[2], dh=dd[3];
    float a0=aa[0], a1=aa[1], a2=aa[2], a3=aa[3];
    float w = __fsub_rn(a2,a0), h = __fsub_rn(a3,a1);
    float cx = __fadd_rn(a0, __fmul_rn(0.5f,w));
    float cy = __fadd_rn(a1, __fmul_rn(0.5f,h));
    float dwc = fminf(dw, BBOX_CLIP_F);
    float dhc = fminf(dh, BBOX_CLIP_F);
    float pcx = __fadd_rn(__fmul_rn(dx,w), cx);
    float pcy = __fadd_rn(__fmul_rn(dy,h), cy);
    float pw = __fmul_rn((float)exp((double)dwc), w);
    float ph = __fmul_rn((float)exp((double)dhc), h);
    float x1 = __fsub_rn(pcx, __fmul_rn(0.5f,pw));
    float y1 = __fsub_rn(pcy, __fmul_rn(0.5f,ph));
    float x2 = __fadd_rn(pcx, __fmul_rn(0.5f,pw));
    float y2 = __fadd_rn(pcy, __fmul_rn(0.5f,ph));
    float x1c=fminf(fmaxf(x1,0.0f),2048.0f);
    float y1c=fminf(fmaxf(y1,0.0f),2048.0f);
    float x2c=fminf(fmaxf(x2,0.0f),2048.0f);
    float y2c=fminf(fmaxf(y2,0.0f),2048.0f);
    bool v = (__fsub_rn(x2c,x1c)>=0.001f) && (__fsub_rn(y2c,y1c)>=0.001f);
    float* bx = (float*)(ws32+BOXA) + 4*s;
    bx[0]=x1c; bx[1]=y1c; bx[2]=x2c; bx[3]=y2c;
    ws32[VALIDA+s] = v?1u:0u;
    valid = v?1u:0u;
    double sg = 1.0/(1.0+exp(-(double)o));
    float sc = (float)sg;
    if (sc < 0.0f) valid = 0u;
    float masked = valid? sc : -1.0f;
    unsigned sm = ~fmono(masked);
    unsigned cp = (unsigned)(l*K_TOP + j);
    key64 = ((unsigned long long)sm<<13) | cp;
    float mx = fmaxf(fmaxf(x1c,y1c),fmaxf(x2c,y2c));
    atomicMax(&ws32[MAXC], __float_as_uint(mx));
  }
  // stable partition over concat order j: valid block then invalid block == key-ascending
  unsigned* pfx = hist;     // hist dead after phase A
  if (t<K_TOP) pfx[j] = valid;
  if (t>=K_TOP) pfx[t] = 0u;
  __syncthreads();
  unsigned incl2 = blockscan1024(pfx[t], wbuf, t);
  if (t==1023) nvS = incl2;
  pfx[t] = incl2;
  __syncthreads();
  if (t<K_TOP){
    unsigned inc = pfx[j];
    unsigned pos = valid? (inc-1u) : (nvS + (unsigned)j - inc);
    ((unsigned long long*)(ws32+KEYS2))[l*K_TOP + pos] = key64;
  }
}

// fused 5-way merge by rank + prep: grank via 4 binary searches (keys unique by cp),
// then write NBSO/AREAS/SORTCP/VALSB directly at the sorted position.
__global__ void k_mergeprep(unsigned* ws32){
  int l = blockIdx.x, t = threadIdx.x;  // 5 blocks x 1024
  const unsigned long long* k2 = (const unsigned long long*)(ws32+KEYS2);
  __shared__ unsigned long long sk[NLEV][K_TOP];   // 40000 B
  for (int m=0;m<NLEV;m++)
    if (t<K_TOP) sk[m][t] = k2[m*K_TOP+t];
  __syncthreads();
  if (t>=K_TOP) return;
  unsigned long long key = sk[l][t];
  int grank = t;
  #pragma unroll
  for (int m=0;m<NLEV;m++){
    if (m==l) continue;
    int lo=0, hi=K_TOP;
    while (lo<hi){ int mid=(lo+hi)>>1; if (sk[m][mid]<key) lo=mid+1; else hi=mid; }
    grank += lo;
  }
  unsigned cp = (unsigned)(key & 0x1FFFULL);
  int j = (int)cp - l*K_TOP;
  int s = (l<<10)|j;
  const float* bx = (const float*)(ws32+BOXA) + 4*s;
  float mc = __uint_as_float(ws32[MAXC]);
  float offv = __fmul_rn((float)l, __fadd_rn(mc,1.0f));
  float n0=__fadd_rn(bx[0],offv), n1=__fadd_rn(bx[1],offv);
  float n2=__fadd_rn(bx[2],offv), n3=__fadd_rn(bx[3],offv);
  float* nb = (float*)(ws32+NBSO) + 4*grank;
  nb[0]=n0; nb[1]=n1; nb[2]=n2; nb[3]=n3;
  ((float*)(ws32+AREAS))[grank] = __fmul_rn(__fsub_rn(n2,n0), __fsub_rn(n3,n1));
  ws32[SORTCP+grank] = cp;
  if (ws32[VALIDA+s]) atomicOr(&ws32[VALSB + (grank>>5)], 1u<<(grank&31));
}

// transposed suppression mask, exact lower-triangle 1D grid (3160 blocks), w-chunk
// boxes staged in LDS; float4 i-box loads.
// maskT[w*NP + i] bit b = IoU(i, 64w+b) > 0.7, computed only for w <= chunk(i)
__global__ void k_mask(unsigned* ws32){
  int b = blockIdx.x;                 // 0..3159
  int c = (int)((sqrtf(8.0f*(float)b+1.0f)-1.0f)*0.5f);
  while ((c+1)*(c+2)/2 <= b) ++c;
  while (c*(c+1)/2 > b) --c;
  int w = b - c*(c+1)/2;              // w <= c
  int tl = threadIdx.x;
  const float* nbS = (const float*)(ws32+NBSO);
  const float* areaS = (const float*)(ws32+AREAS);
  __shared__ float4 jb[64];
  __shared__ float ja[64];
  int jbase = w*64;
  int jcnt = NSEL - jbase; if (jcnt>64) jcnt=64;
  if (tl < jcnt){
    jb[tl] = ((const float4*)nbS)[jbase+tl];
    ja[tl] = areaS[jbase+tl];
  }
  __syncthreads();
  int i = c*64 + tl;
  if (i >= NSEL) return;
  unsigned long long* maskT = (unsigned long long*)(ws32+MASKO);
  float4 bi = ((const float4*)nbS)[i];
  float ai=areaS[i];
  unsigned long long word=0ULL;
  for (int q=0; q<jcnt; ++q){
    float4 bj = jb[q];
    float iw = fmaxf(__fsub_rn(fminf(bj.z,bi.z), fmaxf(bj.x,bi.x)),0.0f);
    float ih = fmaxf(__fsub_rn(fminf(bj.w,bi.w), fmaxf(bj.y,bi.y)),0.0f);
    float inter=__fmul_rn(iw,ih);
    float iou=__fdiv_rn(inter, __fsub_rn(__fadd_rn(ja[q],ai),inter));
    if (iou>0.7f) word |= (1ULL<<q);
  }
  maskT[(size_t)w*NP + i]=word;
}

// chunk-64 gather NMS with early exit at rank>=1000 + fused output gather.
// The lower triangle of the first NSTG chunks (107.5 KB) is prefetched into LDS with
// deep batches of independent loads BEFORE the serial scan -> the scan runs out of LDS
// (no per-chunk L2 latency waves). Chunks >= NSTG (pathological inputs only) fall back
// to the proven predicated global batch-gather.
__global__ void __launch_bounds__(64) k_nms(const unsigned* __restrict__ ws32,
                                            float* __restrict__ out){
  const unsigned long long* maskT = (const unsigned long long*)(ws32+MASKO);
  const unsigned long long* validw = (const unsigned long long*)(ws32+VALSB);
  int lane = threadIdx.x;
  __shared__ unsigned long long colb[NPAIR*64];   // 107,520 B staged triangle
  __shared__ unsigned long long Kb[NW];   // kept word per finished chunk
  __shared__ unsigned long long Vb[NW];   // valid words
  __shared__ unsigned ordl[K_TOP];        // kept sorted-positions (LDS)
  if (lane < NCH) Vb[lane] = validw[lane];
  // ---- stage triangle: pair p=(c,w), w<=c, c<NSTG; 16-deep independent load batches ----
  for (int pb=0; pb<NPAIR; pb+=16){
    unsigned long long v[16];
    #pragma unroll
    for (int k=0;k<16;k++){
      int p = pb+k; if (p>NPAIR-1) p=NPAIR-1;
      int c = (int)((sqrtf(8.0f*(float)p+1.0f)-1.0f)*0.5f);
      while ((c+1)*(c+2)/2 <= p) ++c;
      while (c*(c+1)/2 > p) --c;
      int w = p - c*(c+1)/2;
      v[k] = maskT[(size_t)w*NP + (c<<6) + lane];
    }
    #pragma unroll
    for (int k=0;k<16;k++){
      int p = pb+k; if (p>NPAIR-1) p=NPAIR-1;
      colb[p*64 + lane] = v[k];     // duplicate tail writes hit same addr with same data
    }
  }
  __syncthreads();
  unsigned long long lower = (lane==0)?0ULL:(~0ULL >> (64-lane));
  int rank=0;
  for (int c=0;c<NCH;c++){
    int q = (c<<6) + lane;
    unsigned long long intra, sup=0ULL;
    if (c < NSTG){
      int tb = (c*(c+1))>>1;
      intra = colb[(tb+c)*64 + lane];
      for (int w=0; w<c; ++w)
        sup |= colb[(tb+w)*64 + lane] & Kb[w];
    } else {
      size_t qc = (q < NSEL)? (size_t)q : (size_t)(NSEL-1);  // clamped lanes: valid=0, never kept
      intra = maskT[(size_t)c*NP + qc];
      #pragma unroll
      for (int wb=0; wb<NW; wb+=16){
        if (wb < c){
          unsigned long long v[16];
          #pragma unroll
          for (int k2=0;k2<16;k2++){
            int w = wb+k2;
            int wcl = (w < c)? w : 0;
            v[k2] = maskT[(size_t)wcl*NP + qc];
          }
          #pragma unroll
          for (int k2=0;k2<16;k2++){
            int w = wb+k2;
            sup |= (w < c)? (v[k2] & Kb[w]) : 0ULL;
          }
        }
      }
    }
    unsigned long long valc  = Vb[c];
    bool al = ((valc>>lane)&1ULL) && (sup==0ULL);
    unsigned long long nd = intra & lower;   // smaller-index in-chunk suppressors
    unsigned long long kept = __ballot(al);
    for (int it=0; it<96; ++it){
      bool s2 = (kept & nd) != 0ULL;
      unsigned long long nk = __ballot(al && !s2);
      if (nk==kept) break;
      kept = nk;
    }
    if ((kept>>lane)&1ULL){
      int pos = rank + (int)__popcll(kept & lower);
      if (pos < K_TOP) ordl[pos] = (unsigned)q;
    }
    rank += (int)__popcll(kept);
    if (rank >= K_TOP) break;   // exact: rank>=1000 kept are dropped by ref
    if (lane==0) Kb[c] = kept;
    __syncthreads();
  }
  __syncthreads();
  int cnt = (rank>K_TOP)?K_TOP:rank;
  for (int r=lane; r<K_TOP; r+=64){
    float4 v = make_float4(0.f,0.f,0.f,0.f);
    if (r < cnt){
      unsigned cp = ws32[SORTCP + ordl[r]];
      int l = cp/1000, j = cp - l*1000;
      int s = (l<<10)|j;
      v = ((const float4*)((const float*)(ws32+BOXA)))[s];
    }
    ((float4*)out)[r] = v;
  }
}

extern "C" void kernel_launch(void* const* d_in, const int* in_sizes, int n_in,
                              void* d_out, int out_size, void* d_ws, size_t ws_size,
                              hipStream_t stream){
  const float* obj     = (const float*)d_in[0];
  const float* deltas  = (const float*)d_in[1];
  const float* anchors = (const float*)d_in[2];
  unsigned* ws32 = (unsigned*)d_ws;
  float* out = (float*)d_out;
  (void)in_sizes; (void)n_in; (void)out_size; (void)ws_size;

  hipLaunchKernelGGL(k_hist1,     dim3(512),     dim3(256), 0, stream, obj, ws32);
  hipLaunchKernelGGL(k_red,       dim3(8,18),    dim3(256), 0, stream, ws32);
  hipLaunchKernelGGL(k_collect,   dim3(512),     dim3(256), 0, stream, obj, ws32);
  hipLaunchKernelGGL(k_tailfuse,  dim3(5),       dim3(1024),0, stream, obj, deltas, anchors, ws32);
  hipLaunchKernelGGL(k_mergeprep, dim3(5),       dim3(1024),0, stream, ws32);
  hipLaunchKernelGGL(k_mask,      dim3(3160),    dim3(64),  0, stream, ws32);
  hipLaunchKernelGGL(k_nms,       dim3(1),       dim3(64),  0, stream, ws32, out);
}

// Round 21
// 119.551 us; speedup vs baseline: 1.2663x; 1.2663x over previous
//
#include <hip/hip_runtime.h>
#include <hip/hip_bf16.h>
#include <math.h>

// Problem constants (img 2048x2048, strides 4..64, 3 anchors/loc)
#define K_TOP 1000
#define NLEV  5
#define NSEL  5000          // 5 * 1000 candidates
#define NCH   79            // ceil(5000/64) chunks of 64 candidates
#define NP    5000          // u64 row stride of transposed mask: maskT[w*NP + i]
#define NW    80            // allocated word-rows (0..78 used)
#define ATOT  1047552
#define BBOX_CLIP_F 4.135166556742356f

// ws layout in u32 units
#define INFO1   0          // 5*4: [binstar, above, need, pad]
#define CANDCNT 32         // 5 (own 128B line)
#define EQCNT   64         // 5
#define MAXC    96         // 1 (float bits)
#define DONEC   128        // 5 (k_red election counters)
#define HIST1   256        // 5*2048 reduced hist -> ends 10496
#define CANDO   10496      // 5*1024 per-level local indices -> 15616
#define EQO     15616      // u64[5*4096] = 40960 u32 -> 56576 (byte 62464 %8==0)
#define KEYS2   56576      // u64[5000] = 10000 u32 -> 66576 (byte 226304 %8==0)
#define SORTCP  66576      // u32[5120] -> 71696
#define BOXA    71696      // f32[5120][4] -> 92176
#define VALIDA  92176      // u32[5120] -> 97296
#define NBSO    97296      // f32[5120][4] -> 117776
#define AREAS   117776     // f32[5120] -> 122896
#define VALSB   122896     // u32[160] 5000-bit valid mask (byte 491584 %8==0)
#define MASKO   124080     // u64[NW*NP] (byte 496320 %16==0) -> ends 924080 u32
#define PARTH   1048576    // u32[512*2048] per-block partial hists (byte 4MB, 4MB long)

__device__ __forceinline__ int loff(int l){
  return (l==0)?0:(l==1)?786432:(l==2)?983040:(l==3)?1032192:1044480;
}
// monotonic uint32 key: larger float <-> larger key
__device__ __forceinline__ unsigned fmono(float x){
  unsigned b=__float_as_uint(x);
  return (b&0x80000000u)? ~b : (b|0x80000000u);
}

// inclusive block scan over 1024 threads (shuffle waves + 16-wave combine); 2 barriers.
__device__ __forceinline__ unsigned blockscan1024(unsigned v, unsigned* wbuf, int t){
  int lane = t&63, wid = t>>6;
  #pragma unroll
  for (int d=1; d<64; d<<=1){
    unsigned u = __shfl_up(v, d, 64);
    if (lane>=d) v += u;
  }
  if (lane==63) wbuf[wid]=v;
  __syncthreads();
  if (wid==0){
    unsigned w = (lane<16)? wbuf[lane] : 0u;
    #pragma unroll
    for (int d=1; d<16; d<<=1){
      unsigned u=__shfl_up(w,d,64);
      if (lane>=d) w+=u;
    }
    if (lane<16) wbuf[lane]=w;
  }
  __syncthreads();
  unsigned off = (wid>0)? wbuf[wid-1] : 0u;
  return v+off;
}

// pass-1 histogram (bits 31..21): flat 512-block grid (2048 contiguous elems/block,
// each block inside ONE level since level bounds are multiples of 2048), float4 loads,
// 8x replicated LDS hist. Writes per-block PARTIAL hist (plain coalesced stores).
// FOLDS init: each block zeroes a disjoint 21-word control-region slice.
__global__ void k_hist1(const float* __restrict__ obj, unsigned* ws32){
  int b = blockIdx.x;                 // 512 blocks
  int t = threadIdx.x;                // 256
  if (t<21){
    int idx = b*21 + t;
    if (idx < 10496) ws32[idx]=0u;
    else if (idx < 10656) ws32[VALSB + (idx-10496)]=0u;
  }
  int rep = t & 7;
  __shared__ unsigned h[2048*8];      // 64 KiB replicated hist
  for (int i=t; i<2048*8; i+=256) h[i]=0u;
  __syncthreads();
  const float4* src = (const float4*)(obj + (size_t)b*2048);
  int nVec = (b==511)? 256 : 512;     // tail block has 1024 elems
  for (int i=t; i<nVec; i+=256){
    float4 v = src[i];
    atomicAdd(&h[(fmono(v.x)>>21)*8 + rep], 1u);
    atomicAdd(&h[(fmono(v.y)>>21)*8 + rep], 1u);
    atomicAdd(&h[(fmono(v.z)>>21)*8 + rep], 1u);
    atomicAdd(&h[(fmono(v.w)>>21)*8 + rep], 1u);
  }
  __syncthreads();
  unsigned* dst = ws32 + PARTH + (size_t)b*2048;
  for (int bin=t; bin<2048; bin+=256){
    unsigned v=0;
    #pragma unroll
    for (int r=0;r<8;r++) v += h[bin*8+r];
    dst[bin]=v;                       // plain store; cross-kernel visibility via dispatch order
  }
}

// tiled reduction of partial hists: grid (8 bin-chunks, 18 tiles). Each tile sums <=32
// partials of one level with 4-way unrolled independent accumulators (latency-parallel),
// atomicAdd per NON-ZERO bin. Last tile-block per level runs the descending scan -> INFO1.
__global__ void k_red(unsigned* ws32){
  int c = blockIdx.x;        // 8 bin chunks x 256 bins
  int ty = blockIdx.y;       // 18 tiles
  int t = threadIdx.x;       // 256
  int l, p0, np;
  if (ty<12){ l=0; p0=ty*32; np=32; }
  else if (ty<15){ l=1; p0=384+(ty-12)*32; np=32; }
  else if (ty==15){ l=2; p0=480; np=24; }
  else if (ty==16){ l=3; p0=504; np=6; }
  else { l=4; p0=510; np=2; }
  int bin = (c<<8) + t;
  const unsigned* part = ws32 + PARTH;
  unsigned s0=0,s1=0,s2=0,s3=0;
  int k=0;
  for (; k+4<=np; k+=4){
    s0 += part[(size_t)(p0+k  )*2048 + bin];
    s1 += part[(size_t)(p0+k+1)*2048 + bin];
    s2 += part[(size_t)(p0+k+2)*2048 + bin];
    s3 += part[(size_t)(p0+k+3)*2048 + bin];
  }
  for (; k<np; ++k) s0 += part[(size_t)(p0+k)*2048 + bin];
  unsigned sum = s0+s1+s2+s3;
  if (sum) atomicAdd(&ws32[HIST1 + l*2048 + bin], sum);
  // per-level election (blocks per level: 96,24,8,8,8)
  __shared__ unsigned isLast;
  __shared__ unsigned h2[2048];
  __shared__ unsigned psum[256];
  __threadfence();
  if (t==0){
    unsigned nb = (l==0)?96u:(l==1)?24u:8u;
    unsigned old = atomicAdd(&ws32[DONEC+l],1u);
    isLast = (old==nb-1u)?1u:0u;
  }
  __syncthreads();
  if (!isLast) return;
  __threadfence();
  for (int i=t;i<2048;i+=256) h2[i]=atomicAdd(&ws32[HIST1+l*2048+i],0u);  // coherent re-read
  __syncthreads();
  unsigned local=0;
  for (int r=t*8; r<t*8+8; r++) local += h2[2047-r];
  psum[t]=local; __syncthreads();
  for (int s=1;s<256;s<<=1){
    unsigned v=(t>=s)?psum[t-s]:0u;
    __syncthreads();
    psum[t]+=v;
    __syncthreads();
  }
  unsigned excl=(t==0)?0u:psum[t-1];
  if (excl < K_TOP && psum[t] >= K_TOP){
    unsigned cum=excl;
    for (int r=t*8; r<t*8+8; r++){
      unsigned hv=h2[2047-r];
      if (cum+hv >= K_TOP){
        ws32[INFO1+l*4+0]=(unsigned)(2047-r); // boundary bin b*
        ws32[INFO1+l*4+1]=cum;                // count in strictly greater bins
        ws32[INFO1+l*4+2]=K_TOP-cum;          // needed from bin b*
        break;
      }
      cum+=hv;
    }
  }
}

// single full scan, block-local LDS aggregation: flat 512x2048 grid (one level per
// block). Hits appended to LDS lists; ONE global atomicAdd per list per block at the
// end + bulk copy-out. Order within a level is irrelevant (re-sorted downstream).
__global__ void k_collect(const float* __restrict__ obj, unsigned* ws32){
  int b = blockIdx.x;                 // 512 blocks x 256 threads
  int t = threadIdx.x;
  int l = (b<384)?0:(b<480)?1:(b<504)?2:(b<510)?3:4;
  unsigned bstar = ws32[INFO1 + l*4];
  int lof = loff(l);
  __shared__ unsigned candL[1024];          // per-level greater-bin total < 1000
  __shared__ unsigned long long eqL[2048];
  __shared__ unsigned ncS, neS, b1S, b2S;
  if (t==0){ ncS=0u; neS=0u; }
  __syncthreads();
  const float4* src = (const float4*)(obj + (size_t)b*2048);
  int nVec = (b==511)? 256 : 512;
  for (int i=t; i<nVec; i+=256){
    float4 f = src[i];
    #pragma unroll
    for (int q=0;q<4;q++){
      float x = (q==0)?f.x:(q==1)?f.y:(q==2)?f.z:f.w;
      unsigned key = fmono(x);
      unsigned bin = key>>21;
      unsigned idx = (unsigned)(b*2048 + 4*i + q - lof);
      if (bin > bstar){
        unsigned p = atomicAdd(&ncS,1u);
        if (p<1024u) candL[p]=idx;
      } else if (bin == bstar){
        unsigned p = atomicAdd(&neS,1u);
        if (p<2048u) eqL[p] = (((unsigned long long)(~key))<<20) | idx;
      }
    }
  }
  __syncthreads();
  unsigned nc = ncS>1024u?1024u:ncS, ne = neS>2048u?2048u:neS;
  if (t==0){
    b1S = nc? atomicAdd(&ws32[CANDCNT+l], nc) : 0u;
    b2S = ne? atomicAdd(&ws32[EQCNT+l],  ne) : 0u;
  }
  __syncthreads();
  unsigned base1=b1S, base2=b2S;
  unsigned long long* eq64 = (unsigned long long*)(ws32+EQO) + (size_t)l*4096;
  for (unsigned i=t; i<nc; i+=256){
    unsigned p = base1+i;
    if (p<1024u) ws32[CANDO + l*1024 + p] = candL[i];
  }
  for (unsigned i=t; i<ne; i+=256){
    unsigned p = base2+i;
    if (p<4096u) eq64[p] = eqL[i];
  }
}

// fused per-level (1024 threads, 1 block/level):
//  phase A: exact 4-level radix SELECT of the `need` smallest (m,idx) boundary-bin keys.
//  phase B: rank-sort the 1000 selected, decode+clip+valid+sigmoid, stable valid-partition
//           -> KEYS2 (plain stores; kernel boundary gives visibility to k_mergeprep).
__global__ void k_tailfuse(const float* __restrict__ obj, const float* __restrict__ deltas,
                           const float* __restrict__ anchors, unsigned* ws32){
  int l = blockIdx.x, t = threadIdx.x;   // 5 x 1024
  __shared__ unsigned long long big[4096];    // 32KB: phase A key buf
  __shared__ unsigned long long karr[1024];   // phase-B keys
  __shared__ unsigned hist[2048];             // phase A hist; phase B pfx aliases [0..1023]
  __shared__ unsigned selidx[1024];
  __shared__ unsigned char st[4096];          // 0=TIE 1=SEL 2=REJ
  __shared__ unsigned wbuf[16];
  __shared__ unsigned sdS, scltS, sneeS, scntS, nvS;
  int off = loff(l);
  unsigned cnt = ws32[EQCNT+l]; if (cnt>4096u) cnt=4096u;
  unsigned base = ws32[CANDCNT+l];
  unsigned need = ws32[INFO1+l*4+2];
  const unsigned long long* eq = (const unsigned long long*)(ws32+EQO) + (size_t)l*4096;
  for (int i=t;i<(int)cnt;i+=1024){ big[i]=eq[i]; st[i]=0; }
  if (t==0) sneeS = need;
  __syncthreads();
  // ---- phase A: 4-level radix select ----
  #pragma unroll
  for (int lev=0; lev<4; ++lev){
    int sh = (lev==0)?30:(lev==1)?20:(lev==2)?10:0;
    unsigned msk = (lev==0)?0x7FFu:0x3FFu;
    hist[2*t]=0u; hist[2*t+1]=0u;
    __syncthreads();
    for (int i=t;i<(int)cnt;i+=1024)
      if (st[i]==0) atomicAdd(&hist[(unsigned)((big[i]>>sh)&msk)],1u);
    __syncthreads();
    unsigned h0=hist[2*t], h1=hist[2*t+1];
    unsigned incl = blockscan1024(h0+h1, wbuf, t);
    unsigned cumprev = incl - h0 - h1;
    unsigned needc = sneeS;
    if (cumprev < needc && needc <= cumprev+h0){ sdS=(unsigned)(2*t); scltS=cumprev; }
    else if (cumprev+h0 < needc && needc <= incl){ sdS=(unsigned)(2*t+1); scltS=cumprev+h0; }
    __syncthreads();
    unsigned dstar=sdS, clt=scltS;
    if (t==0) sneeS -= clt;
    for (int i=t;i<(int)cnt;i+=1024){
      if (st[i]==0){
        unsigned d=(unsigned)((big[i]>>sh)&msk);
        st[i] = (d<dstar)?1u: (d>dstar)?2u:0u;
      }
    }
    __syncthreads();
  }
  if (t==0) scntS = base;
  __syncthreads();
  for (int i=t;i<(int)cnt;i+=1024)
    if (st[i]!=2u){ unsigned p=atomicAdd(&scntS,1u); if (p<1024u) selidx[p]=(unsigned)(big[i]&0xFFFFFULL); }
  if (t<(int)base) selidx[t]=ws32[CANDO+l*1024+t];
  __syncthreads();
  // ---- phase B: rank-sort + decode ----
  unsigned idx_t = (t<K_TOP)? selidx[t] : 0u;
  unsigned long long mykey;
  if (t<K_TOP){
    unsigned m = ~fmono(obj[off+idx_t]);
    mykey = (((unsigned long long)m)<<20) | idx_t;
  } else mykey = ~0ULL;
  karr[t]=mykey;
  __syncthreads();
  int j = 0;
  if (t<K_TOP){
    #pragma unroll 4
    for (int u=0; u<K_TOP; ++u) j += (karr[u] < mykey) ? 1 : 0;
  }
  unsigned valid=0u;
  unsigned long long key64=~0ULL;
  int s = (l<<10)|j;
  if (t<K_TOP){
    int g = off + (int)idx_t;
    float o = obj[g];
    const float* dd = deltas + 4*(size_t)g;
    const float* aa = anchors + 4*(size_t)g;
    float dx=dd[0], dy=dd[1], dw=dd[2], dh=dd[3];
    float a0=aa[0], a1=aa[1], a2=aa[2], a3=aa[3];
    float w = __fsub_rn(a2,a0), h = __fsub_rn(a3,a1);
    float cx = __fadd_rn(a0, __fmul_rn(0.5f,w));
    float cy = __fadd_rn(a1, __fmul_rn(0.5f,h));
    float dwc = fminf(dw, BBOX_CLIP_F);
    float dhc = fminf(dh, BBOX_CLIP_F);
    float pcx = __fadd_rn(__fmul_rn(dx,w), cx);
    float pcy = __fadd_rn(__fmul_rn(dy,h), cy);
    float pw = __fmul_rn((float)exp((double)dwc), w);
    float ph = __fmul_rn((float)exp((double)dhc), h);
    float x1 = __fsub_rn(pcx, __fmul_rn(0.5f,pw));
    float y1 = __fsub_rn(pcy, __fmul_rn(0.5f,ph));
    float x2 = __fadd_rn(pcx, __fmul_rn(0.5f,pw));
    float y2 = __fadd_rn(pcy, __fmul_rn(0.5f,ph));
    float x1c=fminf(fmaxf(x1,0.0f),2048.0f);
    float y1c=fminf(fmaxf(y1,0.0f),2048.0f);
    float x2c=fminf(fmaxf(x2,0.0f),2048.0f);
    float y2c=fminf(fmaxf(y2,0.0f),2048.0f);
    bool v = (__fsub_rn(x2c,x1c)>=0.001f) && (__fsub_rn(y2c,y1c)>=0.001f);
    float* bx = (float*)(ws32+BOXA) + 4*s;
    bx[0]=x1c; bx[1]=y1c; bx[2]=x2c; bx[3]=y2c;
    ws32[VALIDA+s] = v?1u:0u;
    valid = v?1u:0u;
    double sg = 1.0/(1.0+exp(-(double)o));
    float sc = (float)sg;
    if (sc < 0.0f) valid = 0u;
    float masked = valid? sc : -1.0f;
    unsigned sm = ~fmono(masked);
    unsigned cp = (unsigned)(l*K_TOP + j);
    key64 = ((unsigned long long)sm<<13) | cp;
    float mx = fmaxf(fmaxf(x1c,y1c),fmaxf(x2c,y2c));
    atomicMax(&ws32[MAXC], __float_as_uint(mx));
  }
  // stable partition over concat order j: valid block then invalid block == key-ascending
  unsigned* pfx = hist;     // hist dead after phase A
  if (t<K_TOP) pfx[j] = valid;
  if (t>=K_TOP) pfx[t] = 0u;
  __syncthreads();
  unsigned incl2 = blockscan1024(pfx[t], wbuf, t);
  if (t==1023) nvS = incl2;
  pfx[t] = incl2;
  __syncthreads();
  if (t<K_TOP){
    unsigned inc = pfx[j];
    unsigned pos = valid? (inc-1u) : (nvS + (unsigned)j - inc);
    ((unsigned long long*)(ws32+KEYS2))[l*K_TOP + pos] = key64;
  }
}

// fused 5-way merge by rank + prep: grank via 4 binary searches (keys unique by cp),
// then write NBSO/AREAS/SORTCP/VALSB directly at the sorted position.
__global__ void k_mergeprep(unsigned* ws32){
  int l = blockIdx.x, t = threadIdx.x;  // 5 blocks x 1024
  const unsigned long long* k2 = (const unsigned long long*)(ws32+KEYS2);
  __shared__ unsigned long long sk[NLEV][K_TOP];   // 40000 B
  for (int m=0;m<NLEV;m++)
    if (t<K_TOP) sk[m][t] = k2[m*K_TOP+t];
  __syncthreads();
  if (t>=K_TOP) return;
  unsigned long long key = sk[l][t];
  int grank = t;
  #pragma unroll
  for (int m=0;m<NLEV;m++){
    if (m==l) continue;
    int lo=0, hi=K_TOP;
    while (lo<hi){ int mid=(lo+hi)>>1; if (sk[m][mid]<key) lo=mid+1; else hi=mid; }
    grank += lo;
  }
  unsigned cp = (unsigned)(key & 0x1FFFULL);
  int j = (int)cp - l*K_TOP;
  int s = (l<<10)|j;
  const float* bx = (const float*)(ws32+BOXA) + 4*s;
  float mc = __uint_as_float(ws32[MAXC]);
  float offv = __fmul_rn((float)l, __fadd_rn(mc,1.0f));
  float n0=__fadd_rn(bx[0],offv), n1=__fadd_rn(bx[1],offv);
  float n2=__fadd_rn(bx[2],offv), n3=__fadd_rn(bx[3],offv);
  float* nb = (float*)(ws32+NBSO) + 4*grank;
  nb[0]=n0; nb[1]=n1; nb[2]=n2; nb[3]=n3;
  ((float*)(ws32+AREAS))[grank] = __fmul_rn(__fsub_rn(n2,n0), __fsub_rn(n3,n1));
  ws32[SORTCP+grank] = cp;
  if (ws32[VALIDA+s]) atomicOr(&ws32[VALSB + (grank>>5)], 1u<<(grank&31));
}

// transposed suppression mask, exact lower-triangle 1D grid (3160 blocks), w-chunk
// boxes staged in LDS; float4 i-box loads.
// maskT[w*NP + i] bit b = IoU(i, 64w+b) > 0.7, computed only for w <= chunk(i)
__global__ void k_mask(unsigned* ws32){
  int b = blockIdx.x;                 // 0..3159
  int c = (int)((sqrtf(8.0f*(float)b+1.0f)-1.0f)*0.5f);
  while ((c+1)*(c+2)/2 <= b) ++c;
  while (c*(c+1)/2 > b) --c;
  int w = b - c*(c+1)/2;              // w <= c
  int tl = threadIdx.x;
  const float* nbS = (const float*)(ws32+NBSO);
  const float* areaS = (const float*)(ws32+AREAS);
  __shared__ float4 jb[64];
  __shared__ float ja[64];
  int jbase = w*64;
  int jcnt = NSEL - jbase; if (jcnt>64) jcnt=64;
  if (tl < jcnt){
    jb[tl] = ((const float4*)nbS)[jbase+tl];
    ja[tl] = areaS[jbase+tl];
  }
  __syncthreads();
  int i = c*64 + tl;
  if (i >= NSEL) return;
  unsigned long long* maskT = (unsigned long long*)(ws32+MASKO);
  float4 bi = ((const float4*)nbS)[i];
  float ai=areaS[i];
  unsigned long long word=0ULL;
  for (int q=0; q<jcnt; ++q){
    float4 bj = jb[q];
    float iw = fmaxf(__fsub_rn(fminf(bj.z,bi.z), fmaxf(bj.x,bi.x)),0.0f);
    float ih = fmaxf(__fsub_rn(fminf(bj.w,bi.w), fmaxf(bj.y,bi.y)),0.0f);
    float inter=__fmul_rn(iw,ih);
    float iou=__fdiv_rn(inter, __fsub_rn(__fadd_rn(ja[q],ai),inter));
    if (iou>0.7f) word |= (1ULL<<q);
  }
  maskT[(size_t)w*NP + i]=word;
}

// chunk-64 gather NMS with early exit at rank>=1000 + fused output gather.
// Sup gather issued as 5 STATIC batches of 16 predicated independent loads (R17-proven).
// Output gather restructured into 3 batched phases (independent loads per phase).
__global__ void __launch_bounds__(64) k_nms(const unsigned* __restrict__ ws32,
                                            float* __restrict__ out){
  const unsigned long long* maskT = (const unsigned long long*)(ws32+MASKO);
  const unsigned long long* validw = (const unsigned long long*)(ws32+VALSB);
  int lane = threadIdx.x;
  __shared__ unsigned long long Kb[NW];   // kept word per finished chunk
  __shared__ unsigned long long Vb[NW];   // valid words
  __shared__ unsigned ordl[K_TOP];        // kept sorted-positions (LDS)
  if (lane < NCH) Vb[lane] = validw[lane];
  __syncthreads();
  unsigned long long lower = (lane==0)?0ULL:(~0ULL >> (64-lane));
  int rank=0;
  for (int c=0;c<NCH;c++){
    int q = (c<<6) + lane;
    size_t qc = (q < NSEL)? (size_t)q : (size_t)(NSEL-1);  // clamped lanes have valid=0, never kept
    unsigned long long intra = maskT[(size_t)c*NP + qc];
    unsigned long long sup=0ULL;
    #pragma unroll
    for (int wb=0; wb<NW; wb+=16){
      if (wb < c){                        // uniform guard; batch needed at all?
        unsigned long long v[16];
        #pragma unroll
        for (int k2=0;k2<16;k2++){
          int w = wb+k2;
          int wcl = (w < c)? w : 0;       // predicate via address clamp (row 0 = L2 broadcast)
          v[k2] = maskT[(size_t)wcl*NP + qc];
        }
        #pragma unroll
        for (int k2=0;k2<16;k2++){
          int w = wb+k2;
          sup |= (w < c)? (v[k2] & Kb[w]) : 0ULL;
        }
      }
    }
    unsigned long long valc  = Vb[c];
    bool al = ((valc>>lane)&1ULL) && (sup==0ULL);
    unsigned long long nd = intra & lower;   // smaller-index in-chunk suppressors
    unsigned long long kept = __ballot(al);
    for (int it=0; it<96; ++it){
      bool s2 = (kept & nd) != 0ULL;
      unsigned long long nk = __ballot(al && !s2);
      if (nk==kept) break;
      kept = nk;
    }
    if ((kept>>lane)&1ULL){
      int pos = rank + (int)__popcll(kept & lower);
      if (pos < K_TOP) ordl[pos] = (unsigned)q;
    }
    rank += (int)__popcll(kept);
    if (rank >= K_TOP) break;   // exact: rank>=1000 kept are dropped by ref
    if (lane==0) Kb[c] = kept;
    __syncthreads();
  }
  __syncthreads();
  int cnt = (rank>K_TOP)?K_TOP:rank;
  // batched output gather: 16 independent SORTCP loads -> 16 independent BOXA loads -> stores
  unsigned cpv[16];
  #pragma unroll
  for (int bq=0; bq<16; bq++){
    int r = lane + (bq<<6);
    cpv[bq] = (r < cnt)? ws32[SORTCP + ordl[r]] : 0u;   // clamp: garbage ordl never dereferenced
  }
  float4 bv[16];
  #pragma unroll
  for (int bq=0; bq<16; bq++){
    unsigned cp = cpv[bq];
    int l = cp/1000, j = cp - l*1000;
    bv[bq] = ((const float4*)((const float*)(ws32+BOXA)))[(l<<10)|j];
  }
  #pragma unroll
  for (int bq=0; bq<16; bq++){
    int r = lane + (bq<<6);
    if (r < K_TOP){
      float4 v = (r < cnt)? bv[bq] : make_float4(0.f,0.f,0.f,0.f);
      ((float4*)out)[r] = v;
    }
  }
}

extern "C" void kernel_launch(void* const* d_in, const int* in_sizes, int n_in,
                              void* d_out, int out_size, void* d_ws, size_t ws_size,
                              hipStream_t stream){
  const float* obj     = (const float*)d_in[0];
  const float* deltas  = (const float*)d_in[1];
  const float* anchors = (const float*)d_in[2];
  unsigned* ws32 = (unsigned*)d_ws;
  float* out = (float*)d_out;
  (void)in_sizes; (void)n_in; (void)out_size; (void)ws_size;

  hipLaunchKernelGGL(k_hist1,     dim3(512),     dim3(256), 0, stream, obj, ws32);
  hipLaunchKernelGGL(k_red,       dim3(8,18),    dim3(256), 0, stream, ws32);
  hipLaunchKernelGGL(k_collect,   dim3(512),     dim3(256), 0, stream, obj, ws32);
  hipLaunchKernelGGL(k_tailfuse,  dim3(5),       dim3(1024),0, stream, obj, deltas, anchors, ws32);
  hipLaunchKernelGGL(k_mergeprep, dim3(5),       dim3(1024),0, stream, ws32);
  hipLaunchKernelGGL(k_mask,      dim3(3160),    dim3(64),  0, stream, ws32);
  hipLaunchKernelGGL(k_nms,       dim3(1),       dim3(64),  0, stream, ws32, out);
}